// Round 8
// baseline (103.402 us; speedup 1.0000x reference)
//
#include <hip/hip_runtime.h>
#include <math.h>

#define NB 8
#define NS 512
#define NE 32
#define DE 256
#define DH 512
#define DA 200
#define DAP 224   // padded att dim (7 tiles of 32)
#define NJ 7
#define NJ_LDS 4  // nj tiles staged in LDS (64 KB); rest read from L2

typedef __bf16 bf16x8 __attribute__((ext_vector_type(8)));
typedef float f32x16 __attribute__((ext_vector_type(16)));

__device__ __forceinline__ float tanh_fast(float x) {
    // tanh(x) = 1 - 2/(exp(2x)+1); raw v_rcp is plenty accurate for logits
    float e = __expf(x + x);
    return fmaf(-2.f, __builtin_amdgcn_rcpf(e + 1.f), 1.f);
}

// ---- stage 1: partial sums of cxt over s-chunks (512 blocks) ----
__global__ __launch_bounds__(256) void cmean_partial(const float* __restrict__ cxt,
                                                     float* __restrict__ psum) {
    const int g = blockIdx.x;       // b*64 + c
    const int b = g >> 6, c = g & 63;
    const int t = threadIdx.x;
    const float* base = cxt + ((size_t)b * NS + c * 8) * DH;
    float s0 = 0.f, s1 = 0.f;
    #pragma unroll
    for (int s = 0; s < 8; ++s) {
        s0 += base[s * DH + t];
        s1 += base[s * DH + t + 256];
    }
    psum[(size_t)g * DH + t]       = s0;
    psum[(size_t)g * DH + t + 256] = s1;
}

// ---- stage 2: reduce partials -> cmean; hatt[b][a] = cmean @ Wh (zero-padded) ----
__global__ __launch_bounds__(256) void hatt_from_psum(const float* __restrict__ psum,
                                                      const float* __restrict__ Wh,
                                                      float* __restrict__ hattw) {
    const int b = blockIdx.x;
    const int t = threadIdx.x;
    __shared__ float cm[DH];
    float s0 = 0.f, s1 = 0.f;
    for (int c = 0; c < 64; ++c) {
        s0 += psum[((size_t)b * 64 + c) * DH + t];
        s1 += psum[((size_t)b * 64 + c) * DH + t + 256];
    }
    cm[t]       = s0 * (1.f / NS);
    cm[t + 256] = s1 * (1.f / NS);
    __syncthreads();
    if (t < DAP) {
        float acc = 0.f;
        if (t < DA)
            for (int h = 0; h < DH; ++h)
                acc = fmaf(cm[h], Wh[h * DA + t], acc);
        hattw[b * DAP + t] = acc;
    }
}

// ---- stage 3: pack We into bf16 B-fragment layout (zero-padded cols) ----
// frag f = nj*16+kk; lane l, elem e: K = kk*16 + (l>>5)*4 + (e&3) + 8*(e>>2),
//                                    n = nj*32 + (l&31)
__global__ __launch_bounds__(64) void wef_build(const float* __restrict__ We,
                                                __bf16* __restrict__ wef) {
    const int f = blockIdx.x;
    const int l = threadIdx.x;
    const int nj = f >> 4, kk = f & 15;
    const int n = nj * 32 + (l & 31);
    bf16x8 v;
    #pragma unroll
    for (int e = 0; e < 8; ++e) {
        int K = kk * 16 + ((l >> 5) << 2) + (e & 3) + 8 * (e >> 2);
        v[e] = (__bf16)((n < DA) ? We[K * DA + n] : 0.f);
    }
    reinterpret_cast<bf16x8*>(wef)[f * 64 + l] = v;
}

// ---- main: 8 waves/block, 2 blocks/CU (64KB LDS), one tile per wave ----
// nj 0..3 B-frags from LDS; nj 4..6 from L2 (latency hidden by 4 waves/SIMD).
__global__ __launch_bounds__(512, 4) void entatt_main(const float* __restrict__ ent,
                                                      const __bf16* __restrict__ wef,
                                                      const float* __restrict__ hattw,
                                                      const float* __restrict__ Ws,
                                                      float* __restrict__ out) {
    const int t    = threadIdx.x;
    const int lane = t & 63;
    const int wid  = t >> 6;            // 0..7
    const int g    = blockIdx.x;        // 0..511
    const int bs   = g * 8 + wid;       // one tile per wave
    const int b    = g >> 6;            // 64 blocks per batch

    __shared__ __bf16 wef_lds[NJ_LDS * 16 * 512];   // 64 KB
    __shared__ float  lg_lds[8][NE];

    // ---- stage nj 0..3 of wef -> LDS (coalesced 16B, once per block) ----
    {
        const float4* s4 = reinterpret_cast<const float4*>(wef);
        float4* d4 = reinterpret_cast<float4*>(wef_lds);
        #pragma unroll
        for (int i = 0; i < 2 * NJ_LDS; ++i) d4[t + i * 512] = s4[t + i * 512];
    }

    const int m  = lane & 31;
    const int hi = lane >> 5;
    const float* eb = ent + (size_t)bs * (NE * DE);

    // ---- A fragments straight from global (32 x 16B in flight, overlaps staging) ----
    bf16x8 A[16];
    #pragma unroll
    for (int kk = 0; kk < 16; ++kk) {
        const float* p = eb + m * DE + kk * 16 + hi * 4;
        float4 u0 = *reinterpret_cast<const float4*>(p);
        float4 u1 = *reinterpret_cast<const float4*>(p + 8);
        bf16x8 v = { (__bf16)u0.x, (__bf16)u0.y, (__bf16)u0.z, (__bf16)u0.w,
                     (__bf16)u1.x, (__bf16)u1.y, (__bf16)u1.z, (__bf16)u1.w };
        A[kk] = v;
    }

    // per-lane att-column scalars for all 7 nj tiles
    const float* hb = hattw + b * DAP;
    float ha_[NJ], wsa_[NJ];
    #pragma unroll
    for (int nj = 0; nj < NJ; ++nj) {
        const int a = nj * 32 + m;
        ha_[nj]  = hb[a];
        wsa_[nj] = (a < DA) ? Ws[a] : 0.f;
    }

    __syncthreads();   // wef_lds ready

    const bf16x8* w8   = reinterpret_cast<const bf16x8*>(wef_lds);
    const bf16x8* wg8  = reinterpret_cast<const bf16x8*>(wef);

    float part[16];
    #pragma unroll
    for (int r = 0; r < 16; ++r) part[r] = 0.f;

    // ---- nj 0..3: B from LDS ----
    #pragma unroll 1
    for (int nj = 0; nj < NJ_LDS; ++nj) {
        f32x16 acc;
        #pragma unroll
        for (int r = 0; r < 16; ++r) acc[r] = 0.f;
        #pragma unroll
        for (int kk = 0; kk < 16; ++kk)
            acc = __builtin_amdgcn_mfma_f32_32x32x16_bf16(
                      A[kk], w8[(nj * 16 + kk) * 64 + lane], acc, 0, 0, 0);
        const float ha = ha_[nj], wsa = wsa_[nj];
        #pragma unroll
        for (int r = 0; r < 16; ++r)
            part[r] = fmaf(tanh_fast(acc[r] + ha), wsa, part[r]);
    }

    // ---- nj 4..6: B from global (L2-resident, 112 KB shared chip-wide) ----
    #pragma unroll 1
    for (int nj = NJ_LDS; nj < NJ; ++nj) {
        f32x16 acc;
        #pragma unroll
        for (int r = 0; r < 16; ++r) acc[r] = 0.f;
        #pragma unroll
        for (int kk = 0; kk < 16; ++kk)
            acc = __builtin_amdgcn_mfma_f32_32x32x16_bf16(
                      A[kk], wg8[(nj * 16 + kk) * 64 + lane], acc, 0, 0, 0);
        const float ha = ha_[nj], wsa = wsa_[nj];
        #pragma unroll
        for (int r = 0; r < 16; ++r)
            part[r] = fmaf(tanh_fast(acc[r] + ha), wsa, part[r]);
    }

    // ---- reduce over the 32 att-cols (within 32-lane groups) ----
    #pragma unroll
    for (int r = 0; r < 16; ++r) {
        float v = part[r];
        v += __shfl_xor(v, 1);  v += __shfl_xor(v, 2);  v += __shfl_xor(v, 4);
        v += __shfl_xor(v, 8);  v += __shfl_xor(v, 16);
        part[r] = v;
    }
    if (m == 0) {
        #pragma unroll
        for (int r = 0; r < 16; ++r)
            lg_lds[wid][(r & 3) + 8 * (r >> 2) + 4 * hi] = part[r];
    }
    // same-wave LDS RAW: compiler inserts lgkmcnt wait; no block barrier needed

    // ---- softmax over entities (streamed from LDS) + fp32 weighted sum ----
    float mx = -1e30f;
    #pragma unroll
    for (int e = 0; e < NE; ++e) mx = fmaxf(mx, lg_lds[wid][e]);

    const float4* eb4 = reinterpret_cast<const float4*>(eb);
    float wsum = 0.f;
    float4 o = make_float4(0.f, 0.f, 0.f, 0.f);
    #pragma unroll
    for (int e = 0; e < NE; ++e) {
        float w = __expf(lg_lds[wid][e] - mx);
        wsum += w;
        float4 v = eb4[e * 64 + lane];
        o.x = fmaf(w, v.x, o.x); o.y = fmaf(w, v.y, o.y);
        o.z = fmaf(w, v.z, o.z); o.w = fmaf(w, v.w, o.w);
    }
    const float inv = __builtin_amdgcn_rcpf(wsum);
    float4 res = make_float4(o.x * inv, o.y * inv, o.z * inv, o.w * inv);
    reinterpret_cast<float4*>(out)[(size_t)bs * 64 + lane] = res;
}

extern "C" void kernel_launch(void* const* d_in, const int* in_sizes, int n_in,
                              void* d_out, int out_size, void* d_ws, size_t ws_size,
                              hipStream_t stream) {
    const float* cxt = (const float*)d_in[0];
    const float* ent = (const float*)d_in[1];
    const float* We  = (const float*)d_in[2];
    const float* Wh  = (const float*)d_in[3];
    const float* Ws  = (const float*)d_in[4];
    float* out = (float*)d_out;

    float*  psum  = (float*)d_ws;                       // 512*512 f32 = 1 MB
    float*  hattw = psum + 512 * DH;                    // 8*224 f32
    __bf16* wef   = (__bf16*)(hattw + NB * DAP);        // 7*16*512 bf16 = 112 KB

    hipLaunchKernelGGL(wef_build, dim3(NJ * 16), dim3(64), 0, stream, We, wef);
    hipLaunchKernelGGL(cmean_partial, dim3(512), dim3(256), 0, stream, cxt, psum);
    hipLaunchKernelGGL(hatt_from_psum, dim3(NB), dim3(256), 0, stream, psum, Wh, hattw);
    hipLaunchKernelGGL(entatt_main, dim3(512), dim3(512), 0, stream,
                       ent, wef, hattw, Ws, out);
}

// Round 11
// 98.867 us; speedup vs baseline: 1.0459x; 1.0459x over previous
//
#include <hip/hip_runtime.h>
#include <math.h>

#define NB 8
#define NS 512
#define NE 32
#define DE 256
#define DH 512
#define DA 200
#define DAP 224   // padded att dim (7 tiles of 32)
#define NJ 7
#define NJ_LDS 4  // nj tiles staged in LDS (64 KB); rest read from L2

typedef __bf16 bf16x8 __attribute__((ext_vector_type(8)));
typedef float f32x16 __attribute__((ext_vector_type(16)));

__device__ __forceinline__ float tanh_fast(float x) {
    // tanh(x) = 1 - 2/(exp(2x)+1); raw v_rcp is plenty accurate for logits
    float e = __expf(x + x);
    return fmaf(-2.f, __builtin_amdgcn_rcpf(e + 1.f), 1.f);
}

// ---- stage 1: partial sums of cxt over s-chunks (512 blocks) ----
__global__ __launch_bounds__(256) void cmean_partial(const float* __restrict__ cxt,
                                                     float* __restrict__ psum) {
    const int g = blockIdx.x;       // b*64 + c
    const int b = g >> 6, c = g & 63;
    const int t = threadIdx.x;
    const float* base = cxt + ((size_t)b * NS + c * 8) * DH;
    float s0 = 0.f, s1 = 0.f;
    #pragma unroll
    for (int s = 0; s < 8; ++s) {
        s0 += base[s * DH + t];
        s1 += base[s * DH + t + 256];
    }
    psum[(size_t)g * DH + t]       = s0;
    psum[(size_t)g * DH + t + 256] = s1;
}

// ---- stage 2: reduce partials -> cmean; hatt[b][a] = cmean @ Wh (zero-padded) ----
__global__ __launch_bounds__(256) void hatt_from_psum(const float* __restrict__ psum,
                                                      const float* __restrict__ Wh,
                                                      float* __restrict__ hattw) {
    const int b = blockIdx.x;
    const int t = threadIdx.x;
    __shared__ float cm[DH];
    float s0 = 0.f, s1 = 0.f;
    for (int c = 0; c < 64; ++c) {
        s0 += psum[((size_t)b * 64 + c) * DH + t];
        s1 += psum[((size_t)b * 64 + c) * DH + t + 256];
    }
    cm[t]       = s0 * (1.f / NS);
    cm[t + 256] = s1 * (1.f / NS);
    __syncthreads();
    if (t < DAP) {
        float acc = 0.f;
        if (t < DA)
            for (int h = 0; h < DH; ++h)
                acc = fmaf(cm[h], Wh[h * DA + t], acc);
        hattw[b * DAP + t] = acc;
    }
}

// ---- stage 3: pack We into bf16 B-fragment layout (zero-padded cols) ----
// frag f = nj*16+kk; lane l, elem e: K = kk*16 + (l>>5)*4 + (e&3) + 8*(e>>2),
//                                    n = nj*32 + (l&31)
__global__ __launch_bounds__(64) void wef_build(const float* __restrict__ We,
                                                __bf16* __restrict__ wef) {
    const int f = blockIdx.x;
    const int l = threadIdx.x;
    const int nj = f >> 4, kk = f & 15;
    const int n = nj * 32 + (l & 31);
    bf16x8 v;
    #pragma unroll
    for (int e = 0; e < 8; ++e) {
        int K = kk * 16 + ((l >> 5) << 2) + (e & 3) + 8 * (e >> 2);
        v[e] = (__bf16)((n < DA) ? We[K * DA + n] : 0.f);
    }
    reinterpret_cast<bf16x8*>(wef)[f * 64 + l] = v;
}

// ---- main: 8 waves/block, 64KB LDS (2 blocks/CU), one tile per wave ----
// nj 0..3 B-frags from LDS; nj 4..6 from L2. launch_bounds(512,2): no VGPR
// squeeze (round 8's (512,4) capped at 64 VGPR -> 35MB spill traffic).
__global__ __launch_bounds__(512, 2) void entatt_main(const float* __restrict__ ent,
                                                      const __bf16* __restrict__ wef,
                                                      const float* __restrict__ hattw,
                                                      const float* __restrict__ Ws,
                                                      float* __restrict__ out) {
    const int t    = threadIdx.x;
    const int lane = t & 63;
    const int wid  = t >> 6;            // 0..7
    const int g    = blockIdx.x;        // 0..511
    const int bs   = g * 8 + wid;       // one tile per wave
    const int b    = g >> 6;            // 64 blocks per batch

    __shared__ __bf16 wef_lds[NJ_LDS * 16 * 512];   // 64 KB
    __shared__ float  lg_lds[8][NE];

    // ---- stage nj 0..3 of wef -> LDS (coalesced 16B, once per block) ----
    {
        const float4* s4 = reinterpret_cast<const float4*>(wef);
        float4* d4 = reinterpret_cast<float4*>(wef_lds);
        #pragma unroll
        for (int i = 0; i < 2 * NJ_LDS; ++i) d4[t + i * 512] = s4[t + i * 512];
    }

    const int m  = lane & 31;
    const int hi = lane >> 5;
    const float* eb = ent + (size_t)bs * (NE * DE);

    // ---- A fragments straight from global (32 x 16B in flight, overlaps staging) ----
    bf16x8 A[16];
    #pragma unroll
    for (int kk = 0; kk < 16; ++kk) {
        const float* p = eb + m * DE + kk * 16 + hi * 4;
        float4 u0 = *reinterpret_cast<const float4*>(p);
        float4 u1 = *reinterpret_cast<const float4*>(p + 8);
        bf16x8 v = { (__bf16)u0.x, (__bf16)u0.y, (__bf16)u0.z, (__bf16)u0.w,
                     (__bf16)u1.x, (__bf16)u1.y, (__bf16)u1.z, (__bf16)u1.w };
        A[kk] = v;
    }

    // per-lane att-column scalars for all 7 nj tiles
    const float* hb = hattw + b * DAP;
    float ha_[NJ], wsa_[NJ];
    #pragma unroll
    for (int nj = 0; nj < NJ; ++nj) {
        const int a = nj * 32 + m;
        ha_[nj]  = hb[a];
        wsa_[nj] = (a < DA) ? Ws[a] : 0.f;
    }

    __syncthreads();   // wef_lds ready

    const bf16x8* w8   = reinterpret_cast<const bf16x8*>(wef_lds);
    const bf16x8* wg8  = reinterpret_cast<const bf16x8*>(wef);

    float part[16];
    #pragma unroll
    for (int r = 0; r < 16; ++r) part[r] = 0.f;

    // ---- nj 0..3: B from LDS ----
    #pragma unroll 1
    for (int nj = 0; nj < NJ_LDS; ++nj) {
        f32x16 acc;
        #pragma unroll
        for (int r = 0; r < 16; ++r) acc[r] = 0.f;
        #pragma unroll
        for (int kk = 0; kk < 16; ++kk)
            acc = __builtin_amdgcn_mfma_f32_32x32x16_bf16(
                      A[kk], w8[(nj * 16 + kk) * 64 + lane], acc, 0, 0, 0);
        const float ha = ha_[nj], wsa = wsa_[nj];
        #pragma unroll
        for (int r = 0; r < 16; ++r)
            part[r] = fmaf(tanh_fast(acc[r] + ha), wsa, part[r]);
    }

    // ---- nj 4..6: B from global (L2-resident, 112 KB shared chip-wide) ----
    #pragma unroll 1
    for (int nj = NJ_LDS; nj < NJ; ++nj) {
        f32x16 acc;
        #pragma unroll
        for (int r = 0; r < 16; ++r) acc[r] = 0.f;
        #pragma unroll
        for (int kk = 0; kk < 16; ++kk)
            acc = __builtin_amdgcn_mfma_f32_32x32x16_bf16(
                      A[kk], wg8[(nj * 16 + kk) * 64 + lane], acc, 0, 0, 0);
        const float ha = ha_[nj], wsa = wsa_[nj];
        #pragma unroll
        for (int r = 0; r < 16; ++r)
            part[r] = fmaf(tanh_fast(acc[r] + ha), wsa, part[r]);
    }

    // ---- reduce over the 32 att-cols (within 32-lane groups) ----
    #pragma unroll
    for (int r = 0; r < 16; ++r) {
        float v = part[r];
        v += __shfl_xor(v, 1);  v += __shfl_xor(v, 2);  v += __shfl_xor(v, 4);
        v += __shfl_xor(v, 8);  v += __shfl_xor(v, 16);
        part[r] = v;
    }
    if (m == 0) {
        #pragma unroll
        for (int r = 0; r < 16; ++r)
            lg_lds[wid][(r & 3) + 8 * (r >> 2) + 4 * hi] = part[r];
    }
    // same-wave LDS RAW: compiler inserts lgkmcnt wait; no block barrier needed

    // ---- softmax over entities (streamed from LDS) + fp32 weighted sum ----
    float mx = -1e30f;
    #pragma unroll
    for (int e = 0; e < NE; ++e) mx = fmaxf(mx, lg_lds[wid][e]);

    const float4* eb4 = reinterpret_cast<const float4*>(eb);
    float wsum = 0.f;
    float4 o = make_float4(0.f, 0.f, 0.f, 0.f);
    #pragma unroll
    for (int e = 0; e < NE; ++e) {
        float w = __expf(lg_lds[wid][e] - mx);
        wsum += w;
        float4 v = eb4[e * 64 + lane];
        o.x = fmaf(w, v.x, o.x); o.y = fmaf(w, v.y, o.y);
        o.z = fmaf(w, v.z, o.z); o.w = fmaf(w, v.w, o.w);
    }
    const float inv = __builtin_amdgcn_rcpf(wsum);
    float4 res = make_float4(o.x * inv, o.y * inv, o.z * inv, o.w * inv);
    reinterpret_cast<float4*>(out)[(size_t)bs * 64 + lane] = res;
}

extern "C" void kernel_launch(void* const* d_in, const int* in_sizes, int n_in,
                              void* d_out, int out_size, void* d_ws, size_t ws_size,
                              hipStream_t stream) {
    const float* cxt = (const float*)d_in[0];
    const float* ent = (const float*)d_in[1];
    const float* We  = (const float*)d_in[2];
    const float* Wh  = (const float*)d_in[3];
    const float* Ws  = (const float*)d_in[4];
    float* out = (float*)d_out;

    float*  psum  = (float*)d_ws;                       // 512*512 f32 = 1 MB
    float*  hattw = psum + 512 * DH;                    // 8*224 f32
    __bf16* wef   = (__bf16*)(hattw + NB * DAP);        // 7*16*512 bf16 = 112 KB

    hipLaunchKernelGGL(wef_build, dim3(NJ * 16), dim3(64), 0, stream, We, wef);
    hipLaunchKernelGGL(cmean_partial, dim3(512), dim3(256), 0, stream, cxt, psum);
    hipLaunchKernelGGL(hatt_from_psum, dim3(NB), dim3(256), 0, stream, psum, Wh, hattw);
    hipLaunchKernelGGL(entatt_main, dim3(512), dim3(512), 0, stream,
                       ent, wef, hattw, Ws, out);
}

// Round 12
// 84.616 us; speedup vs baseline: 1.2220x; 1.1684x over previous
//
#include <hip/hip_runtime.h>
#include <math.h>

#define NB 8
#define NS 512
#define NE 32
#define DE 256
#define DH 512
#define DA 200
#define DAP 224   // padded att dim (7 tiles of 32)
#define NJ 7

typedef __bf16 bf16x8 __attribute__((ext_vector_type(8)));
typedef float f32x16 __attribute__((ext_vector_type(16)));

__device__ __forceinline__ float tanh_fast(float x) {
    // tanh(x) = 1 - 2/(exp(2x)+1); raw v_rcp is plenty accurate for logits
    float e = __expf(x + x);
    return fmaf(-2.f, __builtin_amdgcn_rcpf(e + 1.f), 1.f);
}

// ---- stage 1: partial sums of cxt over s-chunks (512 blocks) ----
__global__ __launch_bounds__(256) void cmean_partial(const float* __restrict__ cxt,
                                                     float* __restrict__ psum) {
    const int g = blockIdx.x;       // b*64 + c
    const int b = g >> 6, c = g & 63;
    const int t = threadIdx.x;
    const float* base = cxt + ((size_t)b * NS + c * 8) * DH;
    float s0 = 0.f, s1 = 0.f;
    #pragma unroll
    for (int s = 0; s < 8; ++s) {
        s0 += base[s * DH + t];
        s1 += base[s * DH + t + 256];
    }
    psum[(size_t)g * DH + t]       = s0;
    psum[(size_t)g * DH + t + 256] = s1;
}

// ---- stage 2: reduce partials -> cmean; hatt[b][a] = cmean @ Wh (zero-padded) ----
__global__ __launch_bounds__(256) void hatt_from_psum(const float* __restrict__ psum,
                                                      const float* __restrict__ Wh,
                                                      float* __restrict__ hattw) {
    const int b = blockIdx.x;
    const int t = threadIdx.x;
    __shared__ float cm[DH];
    float s0 = 0.f, s1 = 0.f;
    for (int c = 0; c < 64; ++c) {
        s0 += psum[((size_t)b * 64 + c) * DH + t];
        s1 += psum[((size_t)b * 64 + c) * DH + t + 256];
    }
    cm[t]       = s0 * (1.f / NS);
    cm[t + 256] = s1 * (1.f / NS);
    __syncthreads();
    if (t < DAP) {
        float acc = 0.f;
        if (t < DA)
            for (int h = 0; h < DH; ++h)
                acc = fmaf(cm[h], Wh[h * DA + t], acc);
        hattw[b * DAP + t] = acc;
    }
}

// ---- stage 3: pack We into bf16 B-fragment layout (zero-padded cols) ----
// frag f = nj*16+kk; lane l, elem e: K = kk*16 + (l>>5)*4 + (e&3) + 8*(e>>2),
//                                    n = nj*32 + (l&31)
__global__ __launch_bounds__(64) void wef_build(const float* __restrict__ We,
                                                __bf16* __restrict__ wef) {
    const int f = blockIdx.x;
    const int l = threadIdx.x;
    const int nj = f >> 4, kk = f & 15;
    const int n = nj * 32 + (l & 31);
    bf16x8 v;
    #pragma unroll
    for (int e = 0; e < 8; ++e) {
        int K = kk * 16 + ((l >> 5) << 2) + (e & 3) + 8 * (e >> 2);
        v[e] = (__bf16)((n < DA) ? We[K * DA + n] : 0.f);
    }
    reinterpret_cast<bf16x8*>(wef)[f * 64 + l] = v;
}

// ---- main: ONE 16-wave block per CU (forced residency), full wef in LDS ----
// 256 blocks x 1024 threads; one (b,s)-tile per wave; no-spill register shape.
// launch_bounds(1024) single-arg: compiler must fit 16 waves/CU (<=128 regs).
__global__ __launch_bounds__(1024) void entatt_main(const float* __restrict__ ent,
                                                    const __bf16* __restrict__ wef,
                                                    const float* __restrict__ hattw,
                                                    const float* __restrict__ Ws,
                                                    float* __restrict__ out) {
    const int t    = threadIdx.x;
    const int lane = t & 63;
    const int wid  = t >> 6;            // 0..15
    const int g    = blockIdx.x;        // 0..255
    const int bs   = g * 16 + wid;      // one tile per wave
    const int b    = g >> 5;            // 32 blocks per batch

    __shared__ __bf16 wef_lds[NJ * 16 * 512];   // 112 KB
    __shared__ float  hatt_lds[DAP];
    __shared__ float  ws_lds[DAP];
    __shared__ float  lg_lds[16][NE];

    // ---- stage full wef -> LDS (coalesced 16B; 7 float4 per thread) ----
    {
        const float4* s4 = reinterpret_cast<const float4*>(wef);
        float4* d4 = reinterpret_cast<float4*>(wef_lds);
        #pragma unroll
        for (int i = 0; i < NJ; ++i) d4[t + i * 1024] = s4[t + i * 1024];
    }
    if (t < DAP) {
        hatt_lds[t] = hattw[b * DAP + t];
        ws_lds[t]   = (t < DA) ? Ws[t] : 0.f;
    }

    const int m  = lane & 31;
    const int hi = lane >> 5;
    const float* eb = ent + (size_t)bs * (NE * DE);

    // ---- A fragments straight from global (32 x 16B in flight, overlaps staging) ----
    bf16x8 A[16];
    #pragma unroll
    for (int kk = 0; kk < 16; ++kk) {
        const float* p = eb + m * DE + kk * 16 + hi * 4;
        float4 u0 = *reinterpret_cast<const float4*>(p);
        float4 u1 = *reinterpret_cast<const float4*>(p + 8);
        bf16x8 v = { (__bf16)u0.x, (__bf16)u0.y, (__bf16)u0.z, (__bf16)u0.w,
                     (__bf16)u1.x, (__bf16)u1.y, (__bf16)u1.z, (__bf16)u1.w };
        A[kk] = v;
    }

    __syncthreads();   // wef_lds / hatt_lds / ws_lds ready

    const bf16x8* w8 = reinterpret_cast<const bf16x8*>(wef_lds);

    // ---- MFMA + fused tanh/Ws partial logits; single acc live at a time ----
    float part[16];
    #pragma unroll
    for (int r = 0; r < 16; ++r) part[r] = 0.f;

    #pragma unroll 1
    for (int nj = 0; nj < NJ; ++nj) {
        f32x16 acc;
        #pragma unroll
        for (int r = 0; r < 16; ++r) acc[r] = 0.f;
        #pragma unroll
        for (int kk = 0; kk < 16; ++kk)
            acc = __builtin_amdgcn_mfma_f32_32x32x16_bf16(
                      A[kk], w8[(nj * 16 + kk) * 64 + lane], acc, 0, 0, 0);
        const float ha  = hatt_lds[nj * 32 + m];
        const float wsa = ws_lds[nj * 32 + m];
        #pragma unroll
        for (int r = 0; r < 16; ++r)
            part[r] = fmaf(tanh_fast(acc[r] + ha), wsa, part[r]);
    }

    // ---- reduce over the 32 att-cols (within 32-lane groups) ----
    #pragma unroll
    for (int r = 0; r < 16; ++r) {
        float v = part[r];
        v += __shfl_xor(v, 1);  v += __shfl_xor(v, 2);  v += __shfl_xor(v, 4);
        v += __shfl_xor(v, 8);  v += __shfl_xor(v, 16);
        part[r] = v;
    }
    if (m == 0) {
        #pragma unroll
        for (int r = 0; r < 16; ++r)
            lg_lds[wid][(r & 3) + 8 * (r >> 2) + 4 * hi] = part[r];
    }
    // same-wave LDS RAW: compiler inserts lgkmcnt wait; no block barrier needed

    // ---- softmax over entities (streamed from LDS) + fp32 weighted sum ----
    float mx = -1e30f;
    #pragma unroll
    for (int e = 0; e < NE; ++e) mx = fmaxf(mx, lg_lds[wid][e]);

    const float4* eb4 = reinterpret_cast<const float4*>(eb);
    float wsum = 0.f;
    float4 o = make_float4(0.f, 0.f, 0.f, 0.f);
    #pragma unroll
    for (int e = 0; e < NE; ++e) {
        float w = __expf(lg_lds[wid][e] - mx);
        wsum += w;
        float4 v = eb4[e * 64 + lane];
        o.x = fmaf(w, v.x, o.x); o.y = fmaf(w, v.y, o.y);
        o.z = fmaf(w, v.z, o.z); o.w = fmaf(w, v.w, o.w);
    }
    const float inv = __builtin_amdgcn_rcpf(wsum);
    float4 res = make_float4(o.x * inv, o.y * inv, o.z * inv, o.w * inv);
    reinterpret_cast<float4*>(out)[(size_t)bs * 64 + lane] = res;
}

extern "C" void kernel_launch(void* const* d_in, const int* in_sizes, int n_in,
                              void* d_out, int out_size, void* d_ws, size_t ws_size,
                              hipStream_t stream) {
    const float* cxt = (const float*)d_in[0];
    const float* ent = (const float*)d_in[1];
    const float* We  = (const float*)d_in[2];
    const float* Wh  = (const float*)d_in[3];
    const float* Ws  = (const float*)d_in[4];
    float* out = (float*)d_out;

    float*  psum  = (float*)d_ws;                       // 512*512 f32 = 1 MB
    float*  hattw = psum + 512 * DH;                    // 8*224 f32
    __bf16* wef   = (__bf16*)(hattw + NB * DAP);        // 7*16*512 bf16 = 112 KB

    hipLaunchKernelGGL(wef_build, dim3(NJ * 16), dim3(64), 0, stream, We, wef);
    hipLaunchKernelGGL(cmean_partial, dim3(512), dim3(256), 0, stream, cxt, psum);
    hipLaunchKernelGGL(hatt_from_psum, dim3(NB), dim3(256), 0, stream, psum, Wh, hattw);
    hipLaunchKernelGGL(entatt_main, dim3(256), dim3(1024), 0, stream,
                       ent, wef, hattw, Ws, out);
}

// Round 13
// 78.510 us; speedup vs baseline: 1.3171x; 1.0778x over previous
//
#include <hip/hip_runtime.h>
#include <math.h>

#define NB 8
#define NS 512
#define NE 32
#define DE 256
#define DH 512
#define DA 200
#define DAP 224   // padded att dim (7 tiles of 32)
#define NJ 7

typedef __bf16 bf16x8 __attribute__((ext_vector_type(8)));
typedef float f32x16 __attribute__((ext_vector_type(16)));

__device__ __forceinline__ float tanh_fast(float x) {
    // tanh(x) = 1 - 2/(exp(2x)+1); raw v_rcp is plenty accurate for logits
    float e = __expf(x + x);
    return fmaf(-2.f, __builtin_amdgcn_rcpf(e + 1.f), 1.f);
}

// ---- stage 1: partial sums of cxt over s-chunks (512 blocks) ----
__global__ __launch_bounds__(256) void cmean_partial(const float* __restrict__ cxt,
                                                     float* __restrict__ psum) {
    const int g = blockIdx.x;       // b*64 + c
    const int b = g >> 6, c = g & 63;
    const int t = threadIdx.x;
    const float* base = cxt + ((size_t)b * NS + c * 8) * DH;
    float s0 = 0.f, s1 = 0.f;
    #pragma unroll
    for (int s = 0; s < 8; ++s) {
        s0 += base[s * DH + t];
        s1 += base[s * DH + t + 256];
    }
    psum[(size_t)g * DH + t]       = s0;
    psum[(size_t)g * DH + t + 256] = s1;
}

// ---- stage 2: reduce partials -> cmean; hatt[b][a] = cmean @ Wh (zero-padded) ----
__global__ __launch_bounds__(256) void hatt_from_psum(const float* __restrict__ psum,
                                                      const float* __restrict__ Wh,
                                                      float* __restrict__ hattw) {
    const int b = blockIdx.x;
    const int t = threadIdx.x;
    __shared__ float cm[DH];
    float s0 = 0.f, s1 = 0.f;
    for (int c = 0; c < 64; ++c) {
        s0 += psum[((size_t)b * 64 + c) * DH + t];
        s1 += psum[((size_t)b * 64 + c) * DH + t + 256];
    }
    cm[t]       = s0 * (1.f / NS);
    cm[t + 256] = s1 * (1.f / NS);
    __syncthreads();
    if (t < DAP) {
        float acc = 0.f;
        if (t < DA)
            for (int h = 0; h < DH; ++h)
                acc = fmaf(cm[h], Wh[h * DA + t], acc);
        hattw[b * DAP + t] = acc;
    }
}

// ---- stage 3: pack We into bf16 B-fragment layout (zero-padded cols) ----
// frag f = nj*16+kk; lane l, elem e: K = kk*16 + (l>>5)*4 + (e&3) + 8*(e>>2),
//                                    n = nj*32 + (l&31)
__global__ __launch_bounds__(64) void wef_build(const float* __restrict__ We,
                                                __bf16* __restrict__ wef) {
    const int f = blockIdx.x;
    const int l = threadIdx.x;
    const int nj = f >> 4, kk = f & 15;
    const int n = nj * 32 + (l & 31);
    bf16x8 v;
    #pragma unroll
    for (int e = 0; e < 8; ++e) {
        int K = kk * 16 + ((l >> 5) << 2) + (e & 3) + 8 * (e >> 2);
        v[e] = (__bf16)((n < DA) ? We[K * DA + n] : 0.f);
    }
    reinterpret_cast<bf16x8*>(wef)[f * 64 + l] = v;
}

// ---- main: ONE 16-wave block per CU, full wef in LDS, one tile per wave ----
// KEY CHANGE vs round 12: A-fragment loads are issued AFTER __syncthreads().
// The compiler drains vmcnt(0) before s_barrier, so pre-barrier A-loads
// serialized the whole CU's 512 KB HBM stream ahead of ALL compute. Post-
// barrier issue lets wave w compute while waves w+1.. still stream (HBM pipe
// overlaps MFMA/VALU pipes).
__global__ __launch_bounds__(1024) void entatt_main(const float* __restrict__ ent,
                                                    const __bf16* __restrict__ wef,
                                                    const float* __restrict__ hattw,
                                                    const float* __restrict__ Ws,
                                                    float* __restrict__ out) {
    const int t    = threadIdx.x;
    const int lane = t & 63;
    const int wid  = t >> 6;            // 0..15
    const int g    = blockIdx.x;        // 0..255
    const int bs   = g * 16 + wid;      // one tile per wave
    const int b    = g >> 5;            // 32 blocks per batch

    __shared__ __bf16 wef_lds[NJ * 16 * 512];   // 112 KB
    __shared__ float  hatt_lds[DAP];
    __shared__ float  ws_lds[DAP];
    __shared__ float  lg_lds[16][NE];

    // ---- stage full wef -> LDS (coalesced 16B; 7 float4 per thread) ----
    {
        const float4* s4 = reinterpret_cast<const float4*>(wef);
        float4* d4 = reinterpret_cast<float4*>(wef_lds);
        #pragma unroll
        for (int i = 0; i < NJ; ++i) d4[t + i * 1024] = s4[t + i * 1024];
    }
    if (t < DAP) {
        hatt_lds[t] = hattw[b * DAP + t];
        ws_lds[t]   = (t < DA) ? Ws[t] : 0.f;
    }

    __syncthreads();   // only staging traffic drains here (L3-hot, cheap)

    const int m  = lane & 31;
    const int hi = lane >> 5;
    const float* eb = ent + (size_t)bs * (NE * DE);

    // ---- A fragments from global, issued post-barrier (overlap across waves) ----
    bf16x8 A[16];
    #pragma unroll
    for (int kk = 0; kk < 16; ++kk) {
        const float* p = eb + m * DE + kk * 16 + hi * 4;
        float4 u0 = *reinterpret_cast<const float4*>(p);
        float4 u1 = *reinterpret_cast<const float4*>(p + 8);
        bf16x8 v = { (__bf16)u0.x, (__bf16)u0.y, (__bf16)u0.z, (__bf16)u0.w,
                     (__bf16)u1.x, (__bf16)u1.y, (__bf16)u1.z, (__bf16)u1.w };
        A[kk] = v;
    }

    const bf16x8* w8 = reinterpret_cast<const bf16x8*>(wef_lds);

    // ---- MFMA + fused tanh/Ws partial logits; single acc live at a time ----
    float part[16];
    #pragma unroll
    for (int r = 0; r < 16; ++r) part[r] = 0.f;

    #pragma unroll 1
    for (int nj = 0; nj < NJ; ++nj) {
        f32x16 acc;
        #pragma unroll
        for (int r = 0; r < 16; ++r) acc[r] = 0.f;
        #pragma unroll
        for (int kk = 0; kk < 16; ++kk)
            acc = __builtin_amdgcn_mfma_f32_32x32x16_bf16(
                      A[kk], w8[(nj * 16 + kk) * 64 + lane], acc, 0, 0, 0);
        const float ha  = hatt_lds[nj * 32 + m];
        const float wsa = ws_lds[nj * 32 + m];
        #pragma unroll
        for (int r = 0; r < 16; ++r)
            part[r] = fmaf(tanh_fast(acc[r] + ha), wsa, part[r]);
    }

    // ---- reduce over the 32 att-cols (within 32-lane groups) ----
    #pragma unroll
    for (int r = 0; r < 16; ++r) {
        float v = part[r];
        v += __shfl_xor(v, 1);  v += __shfl_xor(v, 2);  v += __shfl_xor(v, 4);
        v += __shfl_xor(v, 8);  v += __shfl_xor(v, 16);
        part[r] = v;
    }
    if (m == 0) {
        #pragma unroll
        for (int r = 0; r < 16; ++r)
            lg_lds[wid][(r & 3) + 8 * (r >> 2) + 4 * hi] = part[r];
    }
    // same-wave LDS RAW: compiler inserts lgkmcnt wait; no block barrier needed

    // ---- softmax over entities (streamed from LDS) + fp32 weighted sum ----
    float mx = -1e30f;
    #pragma unroll
    for (int e = 0; e < NE; ++e) mx = fmaxf(mx, lg_lds[wid][e]);

    const float4* eb4 = reinterpret_cast<const float4*>(eb);
    float wsum = 0.f;
    float4 o = make_float4(0.f, 0.f, 0.f, 0.f);
    #pragma unroll
    for (int e = 0; e < NE; ++e) {
        float w = __expf(lg_lds[wid][e] - mx);
        wsum += w;
        float4 v = eb4[e * 64 + lane];
        o.x = fmaf(w, v.x, o.x); o.y = fmaf(w, v.y, o.y);
        o.z = fmaf(w, v.z, o.z); o.w = fmaf(w, v.w, o.w);
    }
    const float inv = __builtin_amdgcn_rcpf(wsum);
    float4 res = make_float4(o.x * inv, o.y * inv, o.z * inv, o.w * inv);
    reinterpret_cast<float4*>(out)[(size_t)bs * 64 + lane] = res;
}

extern "C" void kernel_launch(void* const* d_in, const int* in_sizes, int n_in,
                              void* d_out, int out_size, void* d_ws, size_t ws_size,
                              hipStream_t stream) {
    const float* cxt = (const float*)d_in[0];
    const float* ent = (const float*)d_in[1];
    const float* We  = (const float*)d_in[2];
    const float* Wh  = (const float*)d_in[3];
    const float* Ws  = (const float*)d_in[4];
    float* out = (float*)d_out;

    float*  psum  = (float*)d_ws;                       // 512*512 f32 = 1 MB
    float*  hattw = psum + 512 * DH;                    // 8*224 f32
    __bf16* wef   = (__bf16*)(hattw + NB * DAP);        // 7*16*512 bf16 = 112 KB

    hipLaunchKernelGGL(wef_build, dim3(NJ * 16), dim3(64), 0, stream, We, wef);
    hipLaunchKernelGGL(cmean_partial, dim3(512), dim3(256), 0, stream, cxt, psum);
    hipLaunchKernelGGL(hatt_from_psum, dim3(NB), dim3(256), 0, stream, psum, Wh, hattw);
    hipLaunchKernelGGL(entatt_main, dim3(256), dim3(1024), 0, stream,
                       ent, wef, hattw, Ws, out);
}